// Round 1
// baseline (658.139 us; speedup 1.0000x reference)
//
#include <hip/hip_runtime.h>
#include <cmath>

typedef _Float16 f16;
typedef _Float16 f16x8 __attribute__((ext_vector_type(8)));
typedef float f32x4 __attribute__((ext_vector_type(4)));

#define B_ 128
#define N_ 512
#define H_ 64
#define K_ 16
#define BN_ (B_*N_)

__device__ __forceinline__ float elu_(float x) { return x > 0.f ? x : expm1f(x); }
__device__ __forceinline__ unsigned umin_(unsigned a, unsigned b) { return a < b ? a : b; }
__device__ __forceinline__ f32x4 mfma16(f16x8 a, f16x8 b, f32x4 c) {
    return __builtin_amdgcn_mfma_f32_16x16x32_f16(a, b, c, 0, 0, 0);
}
__device__ __forceinline__ f32x4 splat4(float v) { f32x4 r; r[0]=v; r[1]=v; r[2]=v; r[3]=v; return r; }

// ---------------------------------------------------------------------------
// Generic [rows,64] @ [Kdim,64] GEMM with f16 MFMA, optional elu / sq-norm /
// B-diff (for the EdgeConv P matrix). AMODE 0: A = x fp32, Kdim=5 (padded to 32).
// AMODE 1: A = f16 h, Kdim=64.  Output f16.
// grid 256 x block 256; wave handles 4 sequential 16-row tiles.
// ---------------------------------------------------------------------------
template<int AMODE, bool DOELU, bool DOSQ, bool BDIFF, bool HASBIAS>
__global__ __launch_bounds__(256) void gemm64(const void* __restrict__ Ain,
        const float* __restrict__ W, const float* __restrict__ bias,
        f16* __restrict__ out, float* __restrict__ sqout)
{
    const int lane = threadIdx.x & 63;
    const int wid  = threadIdx.x >> 6;
    const int m = lane & 15, q = lane >> 4;

    // B fragments: lane holds B[k=q*8+jj+32*cc][n=t*16+m]
    f16x8 bf[2][4];
    #pragma unroll
    for (int t = 0; t < 4; ++t) {
        #pragma unroll
        for (int jj = 0; jj < 8; ++jj) {
            if (AMODE == 0) {
                int k = q*8 + jj;
                float v = (k < 5) ? W[k*64 + t*16 + m] : 0.f;
                bf[0][t][jj] = (f16)v;
            } else {
                #pragma unroll
                for (int cc = 0; cc < 2; ++cc) {
                    int k = q*8 + jj + 32*cc;
                    float v = W[k*64 + t*16 + m];
                    if (BDIFF) v -= W[(k+64)*64 + t*16 + m];
                    bf[cc][t][jj] = (f16)v;
                }
            }
        }
    }
    float bcol[4];
    #pragma unroll
    for (int t = 0; t < 4; ++t) bcol[t] = HASBIAS ? bias[t*16 + m] : 0.f;

    const int row0 = blockIdx.x*256 + wid*64;
    for (int rt = 0; rt < 4; ++rt) {
        const int rowbase = row0 + rt*16;
        f16x8 af0, af1;
        if (AMODE == 0) {
            const float* xp = (const float*)Ain + (size_t)(rowbase + m)*5;
            #pragma unroll
            for (int jj = 0; jj < 8; ++jj) {
                int k = q*8 + jj;
                af0[jj] = (k < 5) ? (f16)xp[k] : (f16)0.f;
            }
        } else {
            const f16* Ap = (const f16*)Ain + (size_t)(rowbase + m)*64 + q*8;
            af0 = *(const f16x8*)Ap;
            af1 = *(const f16x8*)(Ap + 32);
        }
        f32x4 acc[4];
        #pragma unroll
        for (int t = 0; t < 4; ++t) acc[t] = splat4(bcol[t]);
        #pragma unroll
        for (int t = 0; t < 4; ++t) acc[t] = mfma16(af0, bf[0][t], acc[t]);
        if (AMODE != 0) {
            #pragma unroll
            for (int t = 0; t < 4; ++t) acc[t] = mfma16(af1, bf[1][t], acc[t]);
        }
        // C/D layout: col = lane&15, row = (lane>>4)*4 + reg
        float s[4] = {0.f, 0.f, 0.f, 0.f};
        #pragma unroll
        for (int t = 0; t < 4; ++t) {
            #pragma unroll
            for (int r = 0; r < 4; ++r) {
                float v = acc[t][r];
                if (DOELU) v = elu_(v);
                out[(size_t)(rowbase + q*4 + r)*64 + t*16 + m] = (f16)v;
                if (DOSQ) s[r] += v*v;
            }
        }
        if (DOSQ) {
            #pragma unroll
            for (int off = 1; off <= 8; off <<= 1) {
                #pragma unroll
                for (int r = 0; r < 4; ++r) s[r] += __shfl_xor(s[r], off);
            }
            if (m == 0) {
                #pragma unroll
                for (int r = 0; r < 4; ++r) sqout[rowbase + q*4 + r] = s[r];
            }
        }
    }
}

// ---------------------------------------------------------------------------
// kNN: per (batch, 16-row tile). Gram strip via MFMA (both waves split the 32
// col-tiles), distance keys (23-bit monotone float | 9-bit col) into LDS,
// then per-row top-16: per-lane Batcher sort-8 + 16x wave-min-of-heads.
// grid 4096 x block 128. LDS 32.9 KB -> 4 wg/CU (8 waves).
// ---------------------------------------------------------------------------
__global__ __launch_bounds__(128) void knn_kernel(const f16* __restrict__ hin,
        const float* __restrict__ sq, int* __restrict__ idxout)
{
    __shared__ unsigned keys[16*514];   // pad 512->514: <=2-way bank aliasing
    const int lane = threadIdx.x & 63;
    const int wid  = threadIdx.x >> 6;  // 0..1
    const int m = lane & 15, q = lane >> 4;
    const int b  = blockIdx.x >> 5;
    const int rt = blockIdx.x & 31;
    const int rowbase = rt*16;
    const f16* hb = hin + (size_t)b*N_*H_;
    const float* sqb = sq + b*N_;

    f16x8 af0, af1;
    {
        const f16* Ap = hb + (size_t)(rowbase + m)*64 + q*8;
        af0 = *(const f16x8*)Ap;
        af1 = *(const f16x8*)(Ap + 32);
    }
    for (int ct = wid; ct < 32; ct += 2) {
        const int colbase = ct*16;
        const f16* Bp = hb + (size_t)(colbase + m)*64 + q*8;  // B[k][n] = h[n][k]
        f16x8 bf0 = *(const f16x8*)Bp;
        f16x8 bf1 = *(const f16x8*)(Bp + 32);
        f32x4 acc = splat4(0.f);
        acc = mfma16(af0, bf0, acc);
        acc = mfma16(af1, bf1, acc);
        const float sc = sqb[colbase + m];
        #pragma unroll
        for (int r = 0; r < 4; ++r) {
            float d = fmaf(-2.f, acc[r], sc);       // sq_i dropped: row-constant
            unsigned u = __float_as_uint(d);
            u = ((int)u < 0) ? ~u : (u | 0x80000000u);   // monotone order map
            unsigned key = (u & 0xFFFFFE00u) | (unsigned)(colbase + m);
            const int rowin = q*4 + r;
            if (colbase + m == rowbase + rowin) key = 0xFFFFFFFFu;  // self mask
            keys[rowin*514 + colbase + m] = key;
        }
    }
    __syncthreads();

    for (int rr = 0; rr < 8; ++rr) {
        const int ri = wid*8 + rr;
        unsigned kk[8];
        #pragma unroll
        for (int s2 = 0; s2 < 8; ++s2) kk[s2] = keys[ri*514 + lane + 64*s2];
        // Batcher odd-even sort of 8 (19 CE)
        #define CE_(a,b2) { unsigned lo = umin_(kk[a],kk[b2]); unsigned hi = kk[a]^kk[b2]^lo; kk[a]=lo; kk[b2]=hi; }
        CE_(0,1) CE_(2,3) CE_(4,5) CE_(6,7)
        CE_(0,2) CE_(1,3) CE_(4,6) CE_(5,7)
        CE_(1,2) CE_(5,6)
        CE_(0,4) CE_(1,5) CE_(2,6) CE_(3,7)
        CE_(2,4) CE_(3,5)
        CE_(1,2) CE_(3,4) CE_(5,6)
        #undef CE_
        unsigned myj = 0;
        #pragma unroll
        for (int it = 0; it < 16; ++it) {
            unsigned mk = kk[0];
            #pragma unroll
            for (int off = 32; off >= 1; off >>= 1) mk = umin_(mk, __shfl_xor(mk, off));
            const bool w = (kk[0] == mk);   // keys unique (embed col idx)
            #pragma unroll
            for (int s2 = 0; s2 < 7; ++s2) kk[s2] = w ? kk[s2+1] : kk[s2];
            kk[7] = w ? 0xFFFFFFFFu : kk[7];
            myj = (lane == it) ? (mk & 511u) : myj;
        }
        if (lane < 16) idxout[((size_t)b*N_ + rowbase + ri)*K_ + lane] = (int)myj;
    }
}

// ---------------------------------------------------------------------------
// EdgeConv layer2 + aggregation: per node n (one wave, 16 nodes per wave):
//   out[n,:] = sum_k elu( elu(P[n]+Q[idx[n,k]]) @ W1 + b1 ),  + fused sq-norm.
// M=16 neighbors, N=64 feats, K=64: 8 MFMAs/node. W1 frags live in registers.
// grid 1024 x block 256.
// ---------------------------------------------------------------------------
__global__ __launch_bounds__(256) void edge_kernel(const f16* __restrict__ P,
        const f16* __restrict__ Q, const int* __restrict__ idx,
        const float* __restrict__ W1, const float* __restrict__ b1,
        f16* __restrict__ out, float* __restrict__ sqout)
{
    const int lane = threadIdx.x & 63;
    const int wid  = threadIdx.x >> 6;
    const int m = lane & 15, q = lane >> 4;

    f16x8 bf[2][4];
    #pragma unroll
    for (int cc = 0; cc < 2; ++cc)
        #pragma unroll
        for (int t = 0; t < 4; ++t)
            #pragma unroll
            for (int jj = 0; jj < 8; ++jj)
                bf[cc][t][jj] = (f16)W1[(q*8 + jj + 32*cc)*64 + t*16 + m];
    float bcol[4];
    #pragma unroll
    for (int t = 0; t < 4; ++t) bcol[t] = b1[t*16 + m];

    const int node0 = blockIdx.x*64 + wid*16;
    for (int i = 0; i < 16; ++i) {
        const int r0 = node0 + i;                 // global node row = b*512+n
        const int j = idx[(size_t)r0*K_ + m];     // lane's neighbor slot = m
        const int qrow = (r0 & ~(N_-1)) + j;
        f16x8 af[2];
        #pragma unroll
        for (int cc = 0; cc < 2; ++cc) {
            const int c0 = q*8 + 32*cc;
            f16x8 pv = *(const f16x8*)(P + (size_t)r0*64 + c0);
            f16x8 qv = *(const f16x8*)(Q + (size_t)qrow*64 + c0);
            #pragma unroll
            for (int jj = 0; jj < 8; ++jj)
                af[cc][jj] = (f16)elu_((float)pv[jj] + (float)qv[jj]);
        }
        f32x4 acc[4];
        #pragma unroll
        for (int t = 0; t < 4; ++t) acc[t] = splat4(bcol[t]);
        #pragma unroll
        for (int cc = 0; cc < 2; ++cc)
            #pragma unroll
            for (int t = 0; t < 4; ++t) acc[t] = mfma16(af[cc], bf[cc][t], acc[t]);
        float ssum = 0.f;
        #pragma unroll
        for (int t = 0; t < 4; ++t) {
            // rows of D = neighbors: elu then sum over all 16 rows
            float s = elu_(acc[t][0]) + elu_(acc[t][1]) + elu_(acc[t][2]) + elu_(acc[t][3]);
            s += __shfl_xor(s, 16);
            s += __shfl_xor(s, 32);
            if (lane < 16) out[(size_t)r0*64 + t*16 + lane] = (f16)s;
            ssum += s*s;
        }
        #pragma unroll
        for (int off = 1; off <= 8; off <<= 1) ssum += __shfl_xor(ssum, off);
        if (lane == 0) sqout[r0] = ssum;
    }
}

// ---------------------------------------------------------------------------
// Global max-pool over nodes + 3-layer output MLP + log_softmax. grid 128.
// ---------------------------------------------------------------------------
__global__ __launch_bounds__(256) void final_kernel(const f16* __restrict__ hin,
        const float* __restrict__ Wo0, const float* __restrict__ bo0,
        const float* __restrict__ Wo1, const float* __restrict__ bo1,
        const float* __restrict__ Wo2, const float* __restrict__ bo2,
        float* __restrict__ out)
{
    __shared__ float red[4][64];
    __shared__ float g0[64], g1[64], g2[64], lg[10];
    const int t = threadIdx.x;
    const int b = blockIdx.x;
    const int f = t & 63, grp = t >> 6;
    float mx = -3.0e38f;
    for (int n = grp; n < N_; n += 4)
        mx = fmaxf(mx, (float)hin[((size_t)b*N_ + n)*64 + f]);
    red[grp][f] = mx;
    __syncthreads();
    if (t < 64) g0[t] = fmaxf(fmaxf(red[0][t], red[1][t]), fmaxf(red[2][t], red[3][t]));
    __syncthreads();
    if (t < 64) { float a = bo0[t]; for (int c = 0; c < 64; ++c) a += g0[c]*Wo0[c*64 + t]; g1[t] = elu_(a); }
    __syncthreads();
    if (t < 64) { float a = bo1[t]; for (int c = 0; c < 64; ++c) a += g1[c]*Wo1[c*64 + t]; g2[t] = elu_(a); }
    __syncthreads();
    if (t < 10) { float a = bo2[t]; for (int c = 0; c < 64; ++c) a += g2[c]*Wo2[c*10 + t]; lg[t] = a; }
    __syncthreads();
    if (t == 0) {
        float mxl = lg[0];
        for (int i = 1; i < 10; ++i) mxl = fmaxf(mxl, lg[i]);
        float s = 0.f;
        for (int i = 0; i < 10; ++i) s += expf(lg[i] - mxl);
        const float lse = mxl + logf(s);
        for (int i = 0; i < 10; ++i) out[b*10 + i] = lg[i] - lse;
    }
}

extern "C" void kernel_launch(void* const* d_in, const int* in_sizes, int n_in,
                              void* d_out, int out_size, void* d_ws, size_t ws_size,
                              hipStream_t stream) {
    const float* x     = (const float*)d_in[0];
    const float* W_in0 = (const float*)d_in[1];
    const float* b_in0 = (const float*)d_in[2];
    const float* W_in1 = (const float*)d_in[3];
    const float* b_in1 = (const float*)d_in[4];
    const float* W_in2 = (const float*)d_in[5];
    const float* b_in2 = (const float*)d_in[6];
    const float* W_e0  = (const float*)d_in[7];   // [2,128,64]
    const float* b_e0  = (const float*)d_in[8];   // [2,64]
    const float* W_e1  = (const float*)d_in[9];   // [2,64,64]
    const float* b_e1  = (const float*)d_in[10];  // [2,64]
    const float* Wo0   = (const float*)d_in[11];
    const float* bo0   = (const float*)d_in[12];
    const float* Wo1   = (const float*)d_in[13];
    const float* bo1   = (const float*)d_in[14];
    const float* Wo2   = (const float*)d_in[15];
    const float* bo2   = (const float*)d_in[16];

    char* ws = (char*)d_ws;
    f16*   hA   = (f16*)(ws);                       // 8 MB
    f16*   hB   = (f16*)(ws + 8388608);             // 8 MB
    f16*   Pb   = (f16*)(ws + 16777216);            // 8 MB
    f16*   Qb   = (f16*)(ws + 25165824);            // 8 MB
    int*   idxb = (int*)(ws + 33554432);            // 4 MB
    float* sqb  = (float*)(ws + 37748736);          // 256 KB

    // input network: x -> hA -> hB -> hA (last fuses sq for block-0 kNN)
    gemm64<0, true,  false, false, true ><<<256, 256, 0, stream>>>(x,  W_in0, b_in0, hA, nullptr);
    gemm64<1, true,  false, false, true ><<<256, 256, 0, stream>>>(hA, W_in1, b_in1, hB, nullptr);
    gemm64<1, true,  true,  false, true ><<<256, 256, 0, stream>>>(hB, W_in2, b_in2, hA, sqb);

    for (int l = 0; l < 2; ++l) {
        const f16* cur = l ? hB : hA;
        f16*       nxt = l ? hA : hB;
        knn_kernel<<<4096, 128, 0, stream>>>(cur, sqb, idxb);
        // P = h @ (W0[:64]-W0[64:]) + b0 ;  Q = h @ W0[64:]
        gemm64<1, false, false, true,  true ><<<256, 256, 0, stream>>>(cur, W_e0 + l*8192,        b_e0 + l*64, Pb, nullptr);
        gemm64<1, false, false, false, false><<<256, 256, 0, stream>>>(cur, W_e0 + l*8192 + 4096, nullptr,     Qb, nullptr);
        edge_kernel<<<1024, 256, 0, stream>>>(Pb, Qb, idxb, W_e1 + l*4096, b_e1 + l*64, nxt, sqb);
    }
    final_kernel<<<128, 256, 0, stream>>>(hA, Wo0, bo0, Wo1, bo1, Wo2, bo2, (float*)d_out);
}

// Round 2
// 490.730 us; speedup vs baseline: 1.3411x; 1.3411x over previous
//
#include <hip/hip_runtime.h>
#include <cmath>

typedef _Float16 f16;
typedef _Float16 f16x8 __attribute__((ext_vector_type(8)));
typedef float f32x4 __attribute__((ext_vector_type(4)));

#define B_ 128
#define N_ 512
#define H_ 64
#define K_ 16
#define BN_ (B_*N_)

__device__ __forceinline__ float elu_(float x) { return x > 0.f ? x : expm1f(x); }
__device__ __forceinline__ unsigned umin_(unsigned a, unsigned b) { return a < b ? a : b; }
__device__ __forceinline__ unsigned umax_(unsigned a, unsigned b) { return a > b ? a : b; }
__device__ __forceinline__ f32x4 mfma16(f16x8 a, f16x8 b, f32x4 c) {
    return __builtin_amdgcn_mfma_f32_16x16x32_f16(a, b, c, 0, 0, 0);
}
__device__ __forceinline__ f32x4 splat4(float v) { f32x4 r; r[0]=v; r[1]=v; r[2]=v; r[3]=v; return r; }

// ---------------------------------------------------------------------------
// Generic [rows,64] @ [Kdim,64] GEMM with f16 MFMA, optional elu / sq-norm /
// B-diff (for the EdgeConv P matrix). AMODE 0: A = x fp32, Kdim=5 (padded).
// AMODE 1: A = f16 h, Kdim=64.  Output f16.
// grid 1024 x block 256; each wave does one 16-row tile (more TLP than R1).
// ---------------------------------------------------------------------------
template<int AMODE, bool DOELU, bool DOSQ, bool BDIFF, bool HASBIAS>
__global__ __launch_bounds__(256) void gemm64(const void* __restrict__ Ain,
        const float* __restrict__ W, const float* __restrict__ bias,
        f16* __restrict__ out, float* __restrict__ sqout)
{
    const int lane = threadIdx.x & 63;
    const int wid  = threadIdx.x >> 6;
    const int m = lane & 15, q = lane >> 4;

    // B fragments: lane holds B[k=q*8+jj+32*cc][n=t*16+m]
    f16x8 bf[2][4];
    #pragma unroll
    for (int t = 0; t < 4; ++t) {
        #pragma unroll
        for (int jj = 0; jj < 8; ++jj) {
            if (AMODE == 0) {
                int k = q*8 + jj;
                float v = (k < 5) ? W[k*64 + t*16 + m] : 0.f;
                bf[0][t][jj] = (f16)v;
            } else {
                #pragma unroll
                for (int cc = 0; cc < 2; ++cc) {
                    int k = q*8 + jj + 32*cc;
                    float v = W[k*64 + t*16 + m];
                    if (BDIFF) v -= W[(k+64)*64 + t*16 + m];
                    bf[cc][t][jj] = (f16)v;
                }
            }
        }
    }
    float bcol[4];
    #pragma unroll
    for (int t = 0; t < 4; ++t) bcol[t] = HASBIAS ? bias[t*16 + m] : 0.f;

    const int rowbase = blockIdx.x*64 + wid*16;
    f16x8 af0, af1;
    if (AMODE == 0) {
        const float* xp = (const float*)Ain + (size_t)(rowbase + m)*5;
        #pragma unroll
        for (int jj = 0; jj < 8; ++jj) {
            int k = q*8 + jj;
            af0[jj] = (k < 5) ? (f16)xp[k] : (f16)0.f;
        }
    } else {
        const f16* Ap = (const f16*)Ain + (size_t)(rowbase + m)*64 + q*8;
        af0 = *(const f16x8*)Ap;
        af1 = *(const f16x8*)(Ap + 32);
    }
    f32x4 acc[4];
    #pragma unroll
    for (int t = 0; t < 4; ++t) acc[t] = splat4(bcol[t]);
    #pragma unroll
    for (int t = 0; t < 4; ++t) acc[t] = mfma16(af0, bf[0][t], acc[t]);
    if (AMODE != 0) {
        #pragma unroll
        for (int t = 0; t < 4; ++t) acc[t] = mfma16(af1, bf[1][t], acc[t]);
    }
    // C/D layout: col = lane&15, row = (lane>>4)*4 + reg
    float s[4] = {0.f, 0.f, 0.f, 0.f};
    #pragma unroll
    for (int t = 0; t < 4; ++t) {
        #pragma unroll
        for (int r = 0; r < 4; ++r) {
            float v = acc[t][r];
            if (DOELU) v = elu_(v);
            out[(size_t)(rowbase + q*4 + r)*64 + t*16 + m] = (f16)v;
            if (DOSQ) s[r] += v*v;
        }
    }
    if (DOSQ) {
        #pragma unroll
        for (int off = 1; off <= 8; off <<= 1) {
            #pragma unroll
            for (int r = 0; r < 4; ++r) s[r] += __shfl_xor(s[r], off);
        }
        if (m == 0) {
            #pragma unroll
            for (int r = 0; r < 4; ++r) sqout[rowbase + q*4 + r] = s[r];
        }
    }
}

// ---------------------------------------------------------------------------
// kNN v2: per (batch, 16-row tile), block 256 (4 waves -> 50% occupancy at
// 33 KB LDS). Gram strip via MFMA (4 waves split 32 col-tiles), monotone
// distance keys into LDS, then per-row top-16 via bitonic merge-reduction:
// sort-8/lane -> pair-merge sorted-16 -> 5 stages of (xor-exchange 16,
// keep-lowest-16 bitonic, merge-16). Short dependency chains, batched shfls.
// Same key set as R1 -> identical neighbor selection.
// grid 4096 x block 256.
// ---------------------------------------------------------------------------
__global__ __launch_bounds__(256, 4) void knn_kernel(const f16* __restrict__ hin,
        const float* __restrict__ sq, int* __restrict__ idxout)
{
    __shared__ unsigned keys[16*514];   // pad 512->514: <=2-way bank aliasing
    const int lane = threadIdx.x & 63;
    const int wid  = threadIdx.x >> 6;  // 0..3
    const int m = lane & 15, q = lane >> 4;
    const int b  = blockIdx.x >> 5;
    const int rt = blockIdx.x & 31;
    const int rowbase = rt*16;
    const f16* hb = hin + (size_t)b*N_*H_;
    const float* sqb = sq + b*N_;

    f16x8 af0, af1;
    {
        const f16* Ap = hb + (size_t)(rowbase + m)*64 + q*8;
        af0 = *(const f16x8*)Ap;
        af1 = *(const f16x8*)(Ap + 32);
    }
    for (int ct = wid; ct < 32; ct += 4) {
        const int colbase = ct*16;
        const f16* Bp = hb + (size_t)(colbase + m)*64 + q*8;  // B[k][n] = h[n][k]
        f16x8 bf0 = *(const f16x8*)Bp;
        f16x8 bf1 = *(const f16x8*)(Bp + 32);
        f32x4 acc = splat4(0.f);
        acc = mfma16(af0, bf0, acc);
        acc = mfma16(af1, bf1, acc);
        const float sc = sqb[colbase + m];
        #pragma unroll
        for (int r = 0; r < 4; ++r) {
            float d = fmaf(-2.f, acc[r], sc);       // sq_i dropped: row-constant
            unsigned u = __float_as_uint(d);
            u = ((int)u < 0) ? ~u : (u | 0x80000000u);   // monotone order map
            unsigned key = (u & 0xFFFFFE00u) | (unsigned)(colbase + m);
            const int rowin = q*4 + r;
            if (colbase + m == rowbase + rowin) key = 0xFFFFFFFFu;  // self mask
            keys[rowin*514 + colbase + m] = key;
        }
    }
    __syncthreads();

    #define CE_(x,y) { unsigned lo_ = umin_(a[x],a[y]); a[y] = umax_(a[x],a[y]); a[x] = lo_; }
    // bitonic merge-16 (input bitonic -> output ascending), 32 CE, depth 4
    #define M16_ \
        CE_(0,8) CE_(1,9) CE_(2,10) CE_(3,11) CE_(4,12) CE_(5,13) CE_(6,14) CE_(7,15) \
        CE_(0,4) CE_(1,5) CE_(2,6) CE_(3,7) CE_(8,12) CE_(9,13) CE_(10,14) CE_(11,15) \
        CE_(0,2) CE_(1,3) CE_(4,6) CE_(5,7) CE_(8,10) CE_(9,11) CE_(12,14) CE_(13,15) \
        CE_(0,1) CE_(2,3) CE_(4,5) CE_(6,7) CE_(8,9) CE_(10,11) CE_(12,13) CE_(14,15)

    for (int rr = 0; rr < 4; ++rr) {
        const int ri = wid*4 + rr;
        unsigned a[16];
        #pragma unroll
        for (int s2 = 0; s2 < 8; ++s2) a[s2] = keys[ri*514 + lane + 64*s2];
        // Batcher odd-even sort-8 ascending (19 CE, depth 6)
        CE_(0,1) CE_(2,3) CE_(4,5) CE_(6,7)
        CE_(0,2) CE_(1,3) CE_(4,6) CE_(5,7)
        CE_(1,2) CE_(5,6)
        CE_(0,4) CE_(1,5) CE_(2,6) CE_(3,7)
        CE_(2,4) CE_(3,5)
        CE_(1,2) CE_(3,4) CE_(5,6)
        // pair-merge: own asc 8 ++ partner's desc 8 = bitonic 16 -> sorted 16
        #pragma unroll
        for (int j = 0; j < 8; ++j) a[8+j] = __shfl_xor(a[7-j], 1);
        M16_
        // 5 stages: exchange sorted-16 with lane^d, keep lowest 16, re-sort
        #pragma unroll
        for (int d = 2; d <= 32; d <<= 1) {
            unsigned u[16];
            #pragma unroll
            for (int j = 0; j < 16; ++j) u[j] = __shfl_xor(a[j], d);
            #pragma unroll
            for (int j = 0; j < 16; ++j) a[j] = umin_(a[j], u[15-j]);  // bitonic lower half
            M16_
        }
        // every lane now holds the sorted global top-16 keys of row ri
        if (lane == 0) {
            int4* op = (int4*)(idxout + ((size_t)b*N_ + rowbase + ri)*K_);
            op[0] = make_int4((int)(a[0]&511u),  (int)(a[1]&511u),  (int)(a[2]&511u),  (int)(a[3]&511u));
            op[1] = make_int4((int)(a[4]&511u),  (int)(a[5]&511u),  (int)(a[6]&511u),  (int)(a[7]&511u));
            op[2] = make_int4((int)(a[8]&511u),  (int)(a[9]&511u),  (int)(a[10]&511u), (int)(a[11]&511u));
            op[3] = make_int4((int)(a[12]&511u), (int)(a[13]&511u), (int)(a[14]&511u), (int)(a[15]&511u));
        }
    }
    #undef CE_
    #undef M16_
}

// ---------------------------------------------------------------------------
// EdgeConv layer2 + aggregation: per node n (one wave, 16 nodes per wave):
//   out[n,:] = sum_k elu( elu(P[n]+Q[idx[n,k]]) @ W1 + b1 ),  + fused sq-norm.
// M=16 neighbors, N=64 feats, K=64: 8 MFMAs/node. W1 frags live in registers.
// grid 1024 x block 256.
// ---------------------------------------------------------------------------
__global__ __launch_bounds__(256) void edge_kernel(const f16* __restrict__ P,
        const f16* __restrict__ Q, const int* __restrict__ idx,
        const float* __restrict__ W1, const float* __restrict__ b1,
        f16* __restrict__ out, float* __restrict__ sqout)
{
    const int lane = threadIdx.x & 63;
    const int wid  = threadIdx.x >> 6;
    const int m = lane & 15, q = lane >> 4;

    f16x8 bf[2][4];
    #pragma unroll
    for (int cc = 0; cc < 2; ++cc)
        #pragma unroll
        for (int t = 0; t < 4; ++t)
            #pragma unroll
            for (int jj = 0; jj < 8; ++jj)
                bf[cc][t][jj] = (f16)W1[(q*8 + jj + 32*cc)*64 + t*16 + m];
    float bcol[4];
    #pragma unroll
    for (int t = 0; t < 4; ++t) bcol[t] = b1[t*16 + m];

    const int node0 = blockIdx.x*64 + wid*16;
    for (int i = 0; i < 16; ++i) {
        const int r0 = node0 + i;                 // global node row = b*512+n
        const int j = idx[(size_t)r0*K_ + m];     // lane's neighbor slot = m
        const int qrow = (r0 & ~(N_-1)) + j;
        f16x8 af[2];
        #pragma unroll
        for (int cc = 0; cc < 2; ++cc) {
            const int c0 = q*8 + 32*cc;
            f16x8 pv = *(const f16x8*)(P + (size_t)r0*64 + c0);
            f16x8 qv = *(const f16x8*)(Q + (size_t)qrow*64 + c0);
            #pragma unroll
            for (int jj = 0; jj < 8; ++jj)
                af[cc][jj] = (f16)elu_((float)pv[jj] + (float)qv[jj]);
        }
        f32x4 acc[4];
        #pragma unroll
        for (int t = 0; t < 4; ++t) acc[t] = splat4(bcol[t]);
        #pragma unroll
        for (int cc = 0; cc < 2; ++cc)
            #pragma unroll
            for (int t = 0; t < 4; ++t) acc[t] = mfma16(af[cc], bf[cc][t], acc[t]);
        float ssum = 0.f;
        #pragma unroll
        for (int t = 0; t < 4; ++t) {
            // rows of D = neighbors: elu then sum over all 16 rows
            float s = elu_(acc[t][0]) + elu_(acc[t][1]) + elu_(acc[t][2]) + elu_(acc[t][3]);
            s += __shfl_xor(s, 16);
            s += __shfl_xor(s, 32);
            if (lane < 16) out[(size_t)r0*64 + t*16 + lane] = (f16)s;
            ssum += s*s;
        }
        #pragma unroll
        for (int off = 1; off <= 8; off <<= 1) ssum += __shfl_xor(ssum, off);
        if (lane == 0) sqout[r0] = ssum;
    }
}

// ---------------------------------------------------------------------------
// Global max-pool over nodes + 3-layer output MLP + log_softmax. grid 128.
// ---------------------------------------------------------------------------
__global__ __launch_bounds__(256) void final_kernel(const f16* __restrict__ hin,
        const float* __restrict__ Wo0, const float* __restrict__ bo0,
        const float* __restrict__ Wo1, const float* __restrict__ bo1,
        const float* __restrict__ Wo2, const float* __restrict__ bo2,
        float* __restrict__ out)
{
    __shared__ float red[4][64];
    __shared__ float g0[64], g1[64], g2[64], lg[10];
    const int t = threadIdx.x;
    const int b = blockIdx.x;
    const int f = t & 63, grp = t >> 6;
    float mx = -3.0e38f;
    for (int n = grp; n < N_; n += 4)
        mx = fmaxf(mx, (float)hin[((size_t)b*N_ + n)*64 + f]);
    red[grp][f] = mx;
    __syncthreads();
    if (t < 64) g0[t] = fmaxf(fmaxf(red[0][t], red[1][t]), fmaxf(red[2][t], red[3][t]));
    __syncthreads();
    if (t < 64) { float a = bo0[t]; for (int c = 0; c < 64; ++c) a += g0[c]*Wo0[c*64 + t]; g1[t] = elu_(a); }
    __syncthreads();
    if (t < 64) { float a = bo1[t]; for (int c = 0; c < 64; ++c) a += g1[c]*Wo1[c*64 + t]; g2[t] = elu_(a); }
    __syncthreads();
    if (t < 10) { float a = bo2[t]; for (int c = 0; c < 64; ++c) a += g2[c]*Wo2[c*10 + t]; lg[t] = a; }
    __syncthreads();
    if (t == 0) {
        float mxl = lg[0];
        for (int i = 1; i < 10; ++i) mxl = fmaxf(mxl, lg[i]);
        float s = 0.f;
        for (int i = 0; i < 10; ++i) s += expf(lg[i] - mxl);
        const float lse = mxl + logf(s);
        for (int i = 0; i < 10; ++i) out[b*10 + i] = lg[i] - lse;
    }
}

extern "C" void kernel_launch(void* const* d_in, const int* in_sizes, int n_in,
                              void* d_out, int out_size, void* d_ws, size_t ws_size,
                              hipStream_t stream) {
    const float* x     = (const float*)d_in[0];
    const float* W_in0 = (const float*)d_in[1];
    const float* b_in0 = (const float*)d_in[2];
    const float* W_in1 = (const float*)d_in[3];
    const float* b_in1 = (const float*)d_in[4];
    const float* W_in2 = (const float*)d_in[5];
    const float* b_in2 = (const float*)d_in[6];
    const float* W_e0  = (const float*)d_in[7];   // [2,128,64]
    const float* b_e0  = (const float*)d_in[8];   // [2,64]
    const float* W_e1  = (const float*)d_in[9];   // [2,64,64]
    const float* b_e1  = (const float*)d_in[10];  // [2,64]
    const float* Wo0   = (const float*)d_in[11];
    const float* bo0   = (const float*)d_in[12];
    const float* Wo1   = (const float*)d_in[13];
    const float* bo1   = (const float*)d_in[14];
    const float* Wo2   = (const float*)d_in[15];
    const float* bo2   = (const float*)d_in[16];

    char* ws = (char*)d_ws;
    f16*   hA   = (f16*)(ws);                       // 8 MB
    f16*   hB   = (f16*)(ws + 8388608);             // 8 MB
    f16*   Pb   = (f16*)(ws + 16777216);            // 8 MB
    f16*   Qb   = (f16*)(ws + 25165824);            // 8 MB
    int*   idxb = (int*)(ws + 33554432);            // 4 MB
    float* sqb  = (float*)(ws + 37748736);          // 256 KB

    // input network: x -> hA -> hB -> hA (last fuses sq for block-0 kNN)
    gemm64<0, true,  false, false, true ><<<1024, 256, 0, stream>>>(x,  W_in0, b_in0, hA, nullptr);
    gemm64<1, true,  false, false, true ><<<1024, 256, 0, stream>>>(hA, W_in1, b_in1, hB, nullptr);
    gemm64<1, true,  true,  false, true ><<<1024, 256, 0, stream>>>(hB, W_in2, b_in2, hA, sqb);

    for (int l = 0; l < 2; ++l) {
        const f16* cur = l ? hB : hA;
        f16*       nxt = l ? hA : hB;
        knn_kernel<<<4096, 256, 0, stream>>>(cur, sqb, idxb);
        // P = h @ (W0[:64]-W0[64:]) + b0 ;  Q = h @ W0[64:]
        gemm64<1, false, false, true,  true ><<<1024, 256, 0, stream>>>(cur, W_e0 + l*8192,        b_e0 + l*64, Pb, nullptr);
        gemm64<1, false, false, false, false><<<1024, 256, 0, stream>>>(cur, W_e0 + l*8192 + 4096, nullptr,     Qb, nullptr);
        edge_kernel<<<1024, 256, 0, stream>>>(Pb, Qb, idxb, W_e1 + l*4096, b_e1 + l*64, nxt, sqb);
    }
    final_kernel<<<128, 256, 0, stream>>>(hA, Wo0, bo0, Wo1, bo1, Wo2, bo2, (float*)d_out);
}

// Round 3
// 342.792 us; speedup vs baseline: 1.9199x; 1.4316x over previous
//
#include <hip/hip_runtime.h>
#include <cmath>

typedef _Float16 f16;
typedef _Float16 f16x8 __attribute__((ext_vector_type(8)));
typedef float f32x4 __attribute__((ext_vector_type(4)));

#define B_ 128
#define N_ 512
#define H_ 64
#define K_ 16

__device__ __forceinline__ float elu_(float x) { return x > 0.f ? x : (__expf(x) - 1.f); }
__device__ __forceinline__ unsigned umin_(unsigned a, unsigned b) { return a < b ? a : b; }
__device__ __forceinline__ unsigned umax_(unsigned a, unsigned b) { return a > b ? a : b; }
__device__ __forceinline__ f32x4 mfma16(f16x8 a, f16x8 b, f32x4 c) {
    return __builtin_amdgcn_mfma_f32_16x16x32_f16(a, b, c, 0, 0, 0);
}
__device__ __forceinline__ f32x4 splat4(float v) { f32x4 r; r[0]=v; r[1]=v; r[2]=v; r[3]=v; return r; }
__device__ __forceinline__ unsigned mbcnt_(unsigned long long mask) {
    return __builtin_amdgcn_mbcnt_hi((unsigned)(mask >> 32),
           __builtin_amdgcn_mbcnt_lo((unsigned)mask, 0u));
}

// 4 interleaved wave-wide bitonic sorts (ascending across 64 lanes, 1 elem/lane).
// Interleaving gives 4-way ILP on the shfl dependency chain.
__device__ __forceinline__ void wsort64x4(unsigned v[4], int lane) {
    #pragma unroll
    for (int k = 2; k <= 64; k <<= 1) {
        #pragma unroll
        for (int j = k >> 1; j >= 1; j >>= 1) {
            const bool takemin = (((lane & k) == 0) == ((lane & j) == 0));
            #pragma unroll
            for (int rr = 0; rr < 4; ++rr) {
                unsigned o = __shfl_xor(v[rr], j);
                unsigned mn = umin_(v[rr], o), mx = umax_(v[rr], o);
                v[rr] = takemin ? mn : mx;
            }
        }
    }
}

// ---------------------------------------------------------------------------
// Fused input MLP (3 layers) + EdgeConv-0 P/Q projections + sq-norms.
// All row-local: per wave one 16-row tile. Layer transitions go C-layout ->
// LDS (row stride 72 f16, 16B-aligned rows) -> A-fragments.
// grid 1024 x block 256.
// ---------------------------------------------------------------------------
__global__ __launch_bounds__(256) void mlp_kernel(const float* __restrict__ x,
        const float* __restrict__ W0, const float* __restrict__ b0,
        const float* __restrict__ W1, const float* __restrict__ b1,
        const float* __restrict__ W2, const float* __restrict__ b2,
        const float* __restrict__ We, const float* __restrict__ be,
        f16* __restrict__ hout, float* __restrict__ sqout,
        f16* __restrict__ Pout, f16* __restrict__ Qout)
{
    __shared__ f16 tile[4][16*72];
    const int lane = threadIdx.x & 63, wid = threadIdx.x >> 6;
    const int m = lane & 15, q = lane >> 4;
    const int rowbase = blockIdx.x*64 + wid*16;
    f16* tw = tile[wid];

    // ---- layer 0: A = x (K=5 padded to 32) ----
    f16x8 af0, af1;
    {
        const float* xp = x + (size_t)(rowbase + m)*5;
        #pragma unroll
        for (int jj = 0; jj < 8; ++jj) { int k = q*8+jj; af0[jj] = (k < 5) ? (f16)xp[k] : (f16)0.f; }
    }
    f32x4 acc[4];
    #pragma unroll
    for (int t = 0; t < 4; ++t) {
        f16x8 bf;
        #pragma unroll
        for (int jj = 0; jj < 8; ++jj) { int k = q*8+jj; bf[jj] = (k < 5) ? (f16)W0[k*64 + t*16+m] : (f16)0.f; }
        acc[t] = splat4(b0[t*16+m]);
        acc[t] = mfma16(af0, bf, acc[t]);
    }
    // transpose (elu applied)
    #pragma unroll
    for (int t = 0; t < 4; ++t)
        #pragma unroll
        for (int r = 0; r < 4; ++r)
            tw[(q*4+r)*72 + t*16+m] = (f16)elu_(acc[t][r]);
    __syncthreads();
    af0 = *(const f16x8*)(tw + m*72 + q*8);
    af1 = *(const f16x8*)(tw + m*72 + q*8 + 32);
    __syncthreads();

    // ---- layer 1 ----
    #pragma unroll
    for (int t = 0; t < 4; ++t) {
        f16x8 bfa, bfb;
        #pragma unroll
        for (int jj = 0; jj < 8; ++jj) {
            bfa[jj] = (f16)W1[(q*8+jj)*64 + t*16+m];
            bfb[jj] = (f16)W1[(q*8+jj+32)*64 + t*16+m];
        }
        acc[t] = splat4(b1[t*16+m]);
        acc[t] = mfma16(af0, bfa, acc[t]);
        acc[t] = mfma16(af1, bfb, acc[t]);
    }
    #pragma unroll
    for (int t = 0; t < 4; ++t)
        #pragma unroll
        for (int r = 0; r < 4; ++r)
            tw[(q*4+r)*72 + t*16+m] = (f16)elu_(acc[t][r]);
    __syncthreads();
    af0 = *(const f16x8*)(tw + m*72 + q*8);
    af1 = *(const f16x8*)(tw + m*72 + q*8 + 32);
    __syncthreads();

    // ---- layer 2 (+ h store, sq, transpose for P/Q) ----
    #pragma unroll
    for (int t = 0; t < 4; ++t) {
        f16x8 bfa, bfb;
        #pragma unroll
        for (int jj = 0; jj < 8; ++jj) {
            bfa[jj] = (f16)W2[(q*8+jj)*64 + t*16+m];
            bfb[jj] = (f16)W2[(q*8+jj+32)*64 + t*16+m];
        }
        acc[t] = splat4(b2[t*16+m]);
        acc[t] = mfma16(af0, bfa, acc[t]);
        acc[t] = mfma16(af1, bfb, acc[t]);
    }
    float vv[4][4];
    float s[4] = {0.f,0.f,0.f,0.f};
    #pragma unroll
    for (int t = 0; t < 4; ++t)
        #pragma unroll
        for (int r = 0; r < 4; ++r) {
            float v = elu_(acc[t][r]);
            vv[t][r] = v;
            hout[(size_t)(rowbase + q*4 + r)*64 + t*16 + m] = (f16)v;
            s[r] += v*v;
        }
    #pragma unroll
    for (int off = 1; off <= 8; off <<= 1) {
        #pragma unroll
        for (int r = 0; r < 4; ++r) s[r] += __shfl_xor(s[r], off);
    }
    if (m == 0) {
        #pragma unroll
        for (int r = 0; r < 4; ++r) sqout[rowbase + q*4 + r] = s[r];
    }
    #pragma unroll
    for (int t = 0; t < 4; ++t)
        #pragma unroll
        for (int r = 0; r < 4; ++r)
            tw[(q*4+r)*72 + t*16+m] = (f16)vv[t][r];
    __syncthreads();
    af0 = *(const f16x8*)(tw + m*72 + q*8);
    af1 = *(const f16x8*)(tw + m*72 + q*8 + 32);

    // ---- P = h@(We[:64]-We[64:]) + be ; Q = h@We[64:] ----
    f32x4 aP[4], aQ[4];
    #pragma unroll
    for (int t = 0; t < 4; ++t) { aP[t] = splat4(be[t*16+m]); aQ[t] = splat4(0.f); }
    #pragma unroll
    for (int cc = 0; cc < 2; ++cc) {
        const f16x8 afc = cc ? af1 : af0;
        #pragma unroll
        for (int t = 0; t < 4; ++t) {
            f16x8 bp, bq;
            #pragma unroll
            for (int jj = 0; jj < 8; ++jj) {
                float wa = We[(q*8+jj+32*cc)*64 + t*16+m];
                float wb = We[(q*8+jj+32*cc+64)*64 + t*16+m];
                bq[jj] = (f16)wb; bp[jj] = (f16)(wa - wb);
            }
            aP[t] = mfma16(afc, bp, aP[t]);
            aQ[t] = mfma16(afc, bq, aQ[t]);
        }
    }
    #pragma unroll
    for (int t = 0; t < 4; ++t)
        #pragma unroll
        for (int r = 0; r < 4; ++r) {
            Pout[(size_t)(rowbase + q*4 + r)*64 + t*16 + m] = (f16)aP[t][r];
            Qout[(size_t)(rowbase + q*4 + r)*64 + t*16 + m] = (f16)aQ[t][r];
        }
}

// ---------------------------------------------------------------------------
// P/Q projection for EdgeConv layer l=1 (reads f16 h). grid 1024 x block 256.
// ---------------------------------------------------------------------------
__global__ __launch_bounds__(256) void pq_kernel(const f16* __restrict__ h,
        const float* __restrict__ We, const float* __restrict__ be,
        f16* __restrict__ Pout, f16* __restrict__ Qout)
{
    const int lane = threadIdx.x & 63, wid = threadIdx.x >> 6;
    const int m = lane & 15, q = lane >> 4;
    const int rowbase = blockIdx.x*64 + wid*16;
    const f16* Ap = h + (size_t)(rowbase + m)*64 + q*8;
    f16x8 af0 = *(const f16x8*)Ap;
    f16x8 af1 = *(const f16x8*)(Ap + 32);
    f32x4 aP[4], aQ[4];
    #pragma unroll
    for (int t = 0; t < 4; ++t) { aP[t] = splat4(be[t*16+m]); aQ[t] = splat4(0.f); }
    #pragma unroll
    for (int cc = 0; cc < 2; ++cc) {
        const f16x8 afc = cc ? af1 : af0;
        #pragma unroll
        for (int t = 0; t < 4; ++t) {
            f16x8 bp, bq;
            #pragma unroll
            for (int jj = 0; jj < 8; ++jj) {
                float wa = We[(q*8+jj+32*cc)*64 + t*16+m];
                float wb = We[(q*8+jj+32*cc+64)*64 + t*16+m];
                bq[jj] = (f16)wb; bp[jj] = (f16)(wa - wb);
            }
            aP[t] = mfma16(afc, bp, aP[t]);
            aQ[t] = mfma16(afc, bq, aQ[t]);
        }
    }
    #pragma unroll
    for (int t = 0; t < 4; ++t)
        #pragma unroll
        for (int r = 0; r < 4; ++r) {
            Pout[(size_t)(rowbase + q*4 + r)*64 + t*16 + m] = (f16)aP[t][r];
            Qout[(size_t)(rowbase + q*4 + r)*64 + t*16 + m] = (f16)aQ[t][r];
        }
}

// ---------------------------------------------------------------------------
// kNN v3: gram strip via MFMA (unchanged), then exact threshold-filtered
// top-16: per-lane min8 -> wave sort64 of minima -> T = 16th-smallest
// (guarantees >=16 keys <= T; top-16 subset of candidates) -> ballot-compact
// candidates (<=64 typical ~18) -> wave sort64 -> lanes 0..15 = top-16.
// Wave-uniform fallback to full bitonic merge if >64 candidates (rare).
// grid 4096 x block 256.
// ---------------------------------------------------------------------------
__global__ __launch_bounds__(256, 4) void knn_kernel(const f16* __restrict__ hin,
        const float* __restrict__ sq, int* __restrict__ idxout)
{
    __shared__ unsigned keys[16*514];      // pad 512->514
    __shared__ unsigned scratch[4][4][64]; // [wave][row][slot]
    const int lane = threadIdx.x & 63;
    const int wid  = threadIdx.x >> 6;     // 0..3
    const int m = lane & 15, q = lane >> 4;
    const int b  = blockIdx.x >> 5;
    const int rt = blockIdx.x & 31;
    const int rowbase = rt*16;
    const f16* hb = hin + (size_t)b*N_*H_;
    const float* sqb = sq + b*N_;

    f16x8 af0, af1;
    {
        const f16* Ap = hb + (size_t)(rowbase + m)*64 + q*8;
        af0 = *(const f16x8*)Ap;
        af1 = *(const f16x8*)(Ap + 32);
    }
    for (int ct = wid; ct < 32; ct += 4) {
        const int colbase = ct*16;
        const f16* Bp = hb + (size_t)(colbase + m)*64 + q*8;
        f16x8 bf0 = *(const f16x8*)Bp;
        f16x8 bf1 = *(const f16x8*)(Bp + 32);
        f32x4 acc = splat4(0.f);
        acc = mfma16(af0, bf0, acc);
        acc = mfma16(af1, bf1, acc);
        const float sc = sqb[colbase + m];
        #pragma unroll
        for (int r = 0; r < 4; ++r) {
            float d = fmaf(-2.f, acc[r], sc);
            unsigned u = __float_as_uint(d);
            u = ((int)u < 0) ? ~u : (u | 0x80000000u);
            unsigned key = (u & 0xFFFFFE00u) | (unsigned)(colbase + m);
            const int rowin = q*4 + r;
            if (colbase + m == rowbase + rowin) key = 0xFFFFFFFFu;  // self
            keys[rowin*514 + colbase + m] = key;
        }
    }
    __syncthreads();

    // load 4 rows x 8 keys
    unsigned kk[4][8];
    #pragma unroll
    for (int rr = 0; rr < 4; ++rr) {
        const int ri = wid*4 + rr;
        #pragma unroll
        for (int s2 = 0; s2 < 8; ++s2) kk[rr][s2] = keys[ri*514 + lane + 64*s2];
    }
    // per-lane minima, interleaved wave sort, threshold
    unsigned v[4];
    #pragma unroll
    for (int rr = 0; rr < 4; ++rr) {
        unsigned mn = kk[rr][0];
        #pragma unroll
        for (int s2 = 1; s2 < 8; ++s2) mn = umin_(mn, kk[rr][s2]);
        v[rr] = mn;
    }
    wsort64x4(v, lane);
    unsigned T[4];
    #pragma unroll
    for (int rr = 0; rr < 4; ++rr) T[rr] = __shfl(v[rr], 15);

    // ballot-compact candidates <= T into scratch (cap 64)
    unsigned cnt[4];
    #pragma unroll
    for (int rr = 0; rr < 4; ++rr) {
        unsigned c = 0;
        #pragma unroll
        for (int s2 = 0; s2 < 8; ++s2) {
            const bool p = kk[rr][s2] <= T[rr];
            unsigned long long bal = __ballot(p);
            unsigned pos = c + mbcnt_(bal);
            if (p && pos < 64u) scratch[wid][rr][pos] = kk[rr][s2];
            c += (unsigned)__popcll(bal);
        }
        cnt[rr] = c;
    }
    __syncthreads();   // uniform; orders scratch writes before cross-lane reads

    unsigned cval[4];
    #pragma unroll
    for (int rr = 0; rr < 4; ++rr)
        cval[rr] = (lane < (int)umin_(cnt[rr], 64u)) ? scratch[wid][rr][lane] : 0xFFFFFFFFu;
    wsort64x4(cval, lane);

    #define CE_(x,y) { unsigned lo_ = umin_(a[x],a[y]); a[y] = umax_(a[x],a[y]); a[x] = lo_; }
    #define M16_ \
        CE_(0,8) CE_(1,9) CE_(2,10) CE_(3,11) CE_(4,12) CE_(5,13) CE_(6,14) CE_(7,15) \
        CE_(0,4) CE_(1,5) CE_(2,6) CE_(3,7) CE_(8,12) CE_(9,13) CE_(10,14) CE_(11,15) \
        CE_(0,2) CE_(1,3) CE_(4,6) CE_(5,7) CE_(8,10) CE_(9,11) CE_(12,14) CE_(13,15) \
        CE_(0,1) CE_(2,3) CE_(4,5) CE_(6,7) CE_(8,9) CE_(10,11) CE_(12,13) CE_(14,15)

    #pragma unroll
    for (int rr = 0; rr < 4; ++rr) {
        const int ri = wid*4 + rr;
        int* outp = idxout + ((size_t)b*N_ + rowbase + ri)*K_;
        if (cnt[rr] <= 64u) {            // wave-uniform fast path
            if (lane < 16) outp[lane] = (int)(cval[rr] & 511u);
        } else {                          // rare exact fallback: full bitonic
            unsigned a[16];
            #pragma unroll
            for (int s2 = 0; s2 < 8; ++s2) a[s2] = kk[rr][s2];
            CE_(0,1) CE_(2,3) CE_(4,5) CE_(6,7)
            CE_(0,2) CE_(1,3) CE_(4,6) CE_(5,7)
            CE_(1,2) CE_(5,6)
            CE_(0,4) CE_(1,5) CE_(2,6) CE_(3,7)
            CE_(2,4) CE_(3,5)
            CE_(1,2) CE_(3,4) CE_(5,6)
            #pragma unroll
            for (int j = 0; j < 8; ++j) a[8+j] = __shfl_xor(a[7-j], 1);
            M16_
            #pragma unroll
            for (int d = 2; d <= 32; d <<= 1) {
                unsigned u2[16];
                #pragma unroll
                for (int j = 0; j < 16; ++j) u2[j] = __shfl_xor(a[j], d);
                #pragma unroll
                for (int j = 0; j < 16; ++j) a[j] = umin_(a[j], u2[15-j]);
                if (d < 32) { M16_ }   // final sort unnecessary: set semantics
            }
            if (lane == 0) {
                #pragma unroll
                for (int j = 0; j < 16; ++j) outp[j] = (int)(a[j] & 511u);
            }
        }
    }
    #undef CE_
    #undef M16_
}

// ---------------------------------------------------------------------------
// EdgeConv layer2 + sum aggregation + fused sq-norm. One node per wave-step.
// grid 1024 x block 256.
// ---------------------------------------------------------------------------
__global__ __launch_bounds__(256) void edge_kernel(const f16* __restrict__ P,
        const f16* __restrict__ Q, const int* __restrict__ idx,
        const float* __restrict__ W1, const float* __restrict__ b1,
        f16* __restrict__ out, float* __restrict__ sqout)
{
    const int lane = threadIdx.x & 63;
    const int wid  = threadIdx.x >> 6;
    const int m = lane & 15, q = lane >> 4;

    f16x8 bf[2][4];
    #pragma unroll
    for (int cc = 0; cc < 2; ++cc)
        #pragma unroll
        for (int t = 0; t < 4; ++t)
            #pragma unroll
            for (int jj = 0; jj < 8; ++jj)
                bf[cc][t][jj] = (f16)W1[(q*8 + jj + 32*cc)*64 + t*16 + m];
    float bcol[4];
    #pragma unroll
    for (int t = 0; t < 4; ++t) bcol[t] = b1[t*16 + m];

    const int node0 = blockIdx.x*64 + wid*16;
    int jv[16];
    #pragma unroll
    for (int i = 0; i < 16; ++i) jv[i] = idx[(size_t)(node0 + i)*K_ + m];

    for (int i = 0; i < 16; ++i) {
        const int r0 = node0 + i;
        const int qrow = (r0 & ~(N_-1)) + jv[i];
        f16x8 af[2];
        #pragma unroll
        for (int cc = 0; cc < 2; ++cc) {
            const int c0 = q*8 + 32*cc;
            f16x8 pv = *(const f16x8*)(P + (size_t)r0*64 + c0);
            f16x8 qv = *(const f16x8*)(Q + (size_t)qrow*64 + c0);
            #pragma unroll
            for (int jj = 0; jj < 8; ++jj)
                af[cc][jj] = (f16)elu_((float)pv[jj] + (float)qv[jj]);
        }
        f32x4 acc[4];
        #pragma unroll
        for (int t = 0; t < 4; ++t) acc[t] = splat4(bcol[t]);
        #pragma unroll
        for (int cc = 0; cc < 2; ++cc)
            #pragma unroll
            for (int t = 0; t < 4; ++t) acc[t] = mfma16(af[cc], bf[cc][t], acc[t]);
        float ssum = 0.f;
        #pragma unroll
        for (int t = 0; t < 4; ++t) {
            float s = elu_(acc[t][0]) + elu_(acc[t][1]) + elu_(acc[t][2]) + elu_(acc[t][3]);
            s += __shfl_xor(s, 16);
            s += __shfl_xor(s, 32);
            if (lane < 16) out[(size_t)r0*64 + t*16 + lane] = (f16)s;
            ssum += s*s;
        }
        #pragma unroll
        for (int off = 1; off <= 8; off <<= 1) ssum += __shfl_xor(ssum, off);
        if (lane == 0) sqout[r0] = ssum;
    }
}

// ---------------------------------------------------------------------------
// Global max-pool + 3-layer output MLP + log_softmax. grid 128.
// ---------------------------------------------------------------------------
__global__ __launch_bounds__(256) void final_kernel(const f16* __restrict__ hin,
        const float* __restrict__ Wo0, const float* __restrict__ bo0,
        const float* __restrict__ Wo1, const float* __restrict__ bo1,
        const float* __restrict__ Wo2, const float* __restrict__ bo2,
        float* __restrict__ out)
{
    __shared__ float red[4][64];
    __shared__ float g0[64], g1[64], g2[64], lg[10];
    const int t = threadIdx.x;
    const int b = blockIdx.x;
    const int f = t & 63, grp = t >> 6;
    float mx = -3.0e38f;
    for (int n = grp; n < N_; n += 4)
        mx = fmaxf(mx, (float)hin[((size_t)b*N_ + n)*64 + f]);
    red[grp][f] = mx;
    __syncthreads();
    if (t < 64) g0[t] = fmaxf(fmaxf(red[0][t], red[1][t]), fmaxf(red[2][t], red[3][t]));
    __syncthreads();
    if (t < 64) { float a = bo0[t]; for (int c = 0; c < 64; ++c) a += g0[c]*Wo0[c*64 + t]; g1[t] = elu_(a); }
    __syncthreads();
    if (t < 64) { float a = bo1[t]; for (int c = 0; c < 64; ++c) a += g1[c]*Wo1[c*64 + t]; g2[t] = elu_(a); }
    __syncthreads();
    if (t < 10) { float a = bo2[t]; for (int c = 0; c < 64; ++c) a += g2[c]*Wo2[c*10 + t]; lg[t] = a; }
    __syncthreads();
    if (t == 0) {
        float mxl = lg[0];
        for (int i = 1; i < 10; ++i) mxl = fmaxf(mxl, lg[i]);
        float s = 0.f;
        for (int i = 0; i < 10; ++i) s += expf(lg[i] - mxl);
        const float lse = mxl + logf(s);
        for (int i = 0; i < 10; ++i) out[b*10 + i] = lg[i] - lse;
    }
}

extern "C" void kernel_launch(void* const* d_in, const int* in_sizes, int n_in,
                              void* d_out, int out_size, void* d_ws, size_t ws_size,
                              hipStream_t stream) {
    const float* x     = (const float*)d_in[0];
    const float* W_in0 = (const float*)d_in[1];
    const float* b_in0 = (const float*)d_in[2];
    const float* W_in1 = (const float*)d_in[3];
    const float* b_in1 = (const float*)d_in[4];
    const float* W_in2 = (const float*)d_in[5];
    const float* b_in2 = (const float*)d_in[6];
    const float* W_e0  = (const float*)d_in[7];   // [2,128,64]
    const float* b_e0  = (const float*)d_in[8];   // [2,64]
    const float* W_e1  = (const float*)d_in[9];   // [2,64,64]
    const float* b_e1  = (const float*)d_in[10];  // [2,64]
    const float* Wo0   = (const float*)d_in[11];
    const float* bo0   = (const float*)d_in[12];
    const float* Wo1   = (const float*)d_in[13];
    const float* bo1   = (const float*)d_in[14];
    const float* Wo2   = (const float*)d_in[15];
    const float* bo2   = (const float*)d_in[16];

    char* ws = (char*)d_ws;
    f16*   hA   = (f16*)(ws);                       // 8 MB
    f16*   hB   = (f16*)(ws + 8388608);             // 8 MB
    f16*   Pb   = (f16*)(ws + 16777216);            // 8 MB
    f16*   Qb   = (f16*)(ws + 25165824);            // 8 MB
    int*   idxb = (int*)(ws + 33554432);            // 4 MB
    float* sqb  = (float*)(ws + 37748736);          // 256 KB

    // fused input MLP + P0/Q0 + sq
    mlp_kernel<<<1024, 256, 0, stream>>>(x, W_in0, b_in0, W_in1, b_in1, W_in2, b_in2,
                                         W_e0, b_e0, hA, sqb, Pb, Qb);
    // block 0
    knn_kernel<<<4096, 256, 0, stream>>>(hA, sqb, idxb);
    edge_kernel<<<1024, 256, 0, stream>>>(Pb, Qb, idxb, W_e1, b_e1, hB, sqb);
    // block 1
    pq_kernel<<<1024, 256, 0, stream>>>(hB, W_e0 + 8192, b_e0 + 64, Pb, Qb);
    knn_kernel<<<4096, 256, 0, stream>>>(hB, sqb, idxb);
    edge_kernel<<<1024, 256, 0, stream>>>(Pb, Qb, idxb, W_e1 + 4096, b_e1 + 64, hA, sqb);

    final_kernel<<<128, 256, 0, stream>>>(hA, Wo0, bo0, Wo1, bo1, Wo2, bo2, (float*)d_out);
}